// Round 10
// baseline (596.831 us; speedup 1.0000x reference)
//
#include <hip/hip_runtime.h>
#include <hip/hip_bf16.h>

#define Mdim 8192
#define Ndim 16384
#define Ennz 2097152
#define Bsz 8
#define Jit 3
#define IMG 128
#define RCAP 512
#define CCAP 256

typedef __attribute__((ext_vector_type(8))) short bf8_t;   // 8 bf16 = 4 VGPRs
typedef __attribute__((ext_vector_type(4))) float f4_t;

__device__ __forceinline__ short f2b(float f){
    __hip_bfloat16 h = __float2bfloat16(f);
    return *reinterpret_cast<short*>(&h);
}

// ---- zero the 24576 bucket counters ----
__global__ void k_zeroc(int* cnt){
    int i = blockIdx.x*256 + threadIdx.x;
    cnt[i] = 0;
}

// ---- phase 1: CSR buckets only. Per-XCD write region = 4 MB = L2 size.
// Non-temporal input reads keep L2 free for bucket-line accumulation.
__global__ __launch_bounds__(256) void k_build_r(const float* __restrict__ vals,
                        const int* __restrict__ rows, const int* __restrict__ cols,
                        int* row_cnt, float2* rp){
    int g  = blockIdx.x & 7;
    int wg = blockIdx.x >> 3;            // 128 blocks per group
    int base = wg * (Ennz/128);
    int r_lo = g*1024;
    for(int k = threadIdx.x; k < Ennz/128; k += 256){
        int e = base + k;
        int r = __builtin_nontemporal_load(rows + e);
        if((unsigned)(r - r_lo) < 1024u){
            float v = __builtin_nontemporal_load(vals + e);
            int c = __builtin_nontemporal_load(cols + e);
            int pr = atomicAdd(&row_cnt[r], 1);
            if(pr < RCAP) rp[(size_t)r*RCAP + pr] = make_float2(v, __int_as_float(c));
        }
    }
}

// ---- phase 2: CSC buckets only ----
__global__ __launch_bounds__(256) void k_build_c(const float* __restrict__ vals,
                        const int* __restrict__ rows, const int* __restrict__ cols,
                        int* col_cnt, float2* cp){
    int g  = blockIdx.x & 7;
    int wg = blockIdx.x >> 3;
    int base = wg * (Ennz/128);
    int c_lo = g*2048;
    for(int k = threadIdx.x; k < Ennz/128; k += 256){
        int e = base + k;
        int c = __builtin_nontemporal_load(cols + e);
        if((unsigned)(c - c_lo) < 2048u){
            float v = __builtin_nontemporal_load(vals + e);
            int r = __builtin_nontemporal_load(rows + e);
            int pc = atomicAdd(&col_cnt[c], 1);
            if(pc < CCAP) cp[(size_t)c*CCAP + pc] = make_float2(v, __int_as_float(r));
        }
    }
}

// ---- pre-convert weights to bf16 once: w2p [j][kk*32+oc][ic pad 40], w3p [j][288] ----
__global__ void k_prep(const float* __restrict__ W2, const float* __restrict__ W3,
                       short* __restrict__ w2p, short* __restrict__ w3p){
    int i = blockIdx.x*256 + threadIdx.x;
    if(i < 3*9216){
        int j = i / 9216, idx = i - j*9216;
        int kk = idx >> 10, rem = idx & 1023;
        int ic = rem >> 5, oc = rem & 31;
        w2p[(size_t)j*11520 + (kk*32 + oc)*40 + ic] = f2b(W2[i]);
    }
    if(i < 3*288) w3p[i] = f2b(W3[i]);
}

// ---- init: z_cur <- z_in, zu_T[n*8+b] <- z*u ----
__global__ void k_init(const float* __restrict__ z_in, const float* __restrict__ u,
                       float* __restrict__ z_cur, float* __restrict__ zu_T){
    int i = blockIdx.x*256 + threadIdx.x;
    int n = i >> 3, b = i & 7;
    float z = z_in[b*Ndim + n];
    z_cur[b*Ndim + n] = z;
    zu_T[i] = z * u[b*Ndim + n];
}

// ---- gather-SpMM 1 (+ zero ssq for this iteration's norm) ----
__global__ void k_spmm1g(const float2* __restrict__ rp, const int* __restrict__ row_cnt,
                         const float* __restrict__ y, const float* __restrict__ zu_T,
                         float* __restrict__ resid_T, float* __restrict__ ssq){
    if(blockIdx.x == 0 && threadIdx.x < 8) ssq[threadIdx.x] = 0.f;
    int m = (blockIdx.x*256 + threadIdx.x) >> 6;
    int lane = threadIdx.x & 63;
    int n_nz = min(row_cnt[m], RCAP);
    int b = lane & 7, ks = lane >> 3;
    const float2* base = rp + (size_t)m*RCAP;
    float acc = 0.f;
    for(int k = ks; k < n_nz; k += 8){
        float2 t = base[k];
        acc = fmaf(t.x, zu_T[__float_as_int(t.y)*8 + b], acc);
    }
    acc += __shfl_xor(acc, 8);
    acc += __shfl_xor(acc, 16);
    acc += __shfl_xor(acc, 32);
    if(ks == 0)
        resid_T[m*8 + b] = y[b*Mdim + m] - acc;
}

// ---- gather-SpMM 2 ----
__global__ void k_spmm2g(const float2* __restrict__ cp, const int* __restrict__ col_cnt,
                         const float* __restrict__ resid_T, float* __restrict__ v_T){
    int n = (blockIdx.x*256 + threadIdx.x) >> 6;
    int lane = threadIdx.x & 63;
    int n_nz = min(col_cnt[n], CCAP);
    int b = lane & 7, ks = lane >> 3;
    const float2* base = cp + (size_t)n*CCAP;
    float acc = 0.f;
    for(int k = ks; k < n_nz; k += 8){
        float2 t = base[k];
        acc = fmaf(t.x, resid_T[__float_as_int(t.y)*8 + b], acc);
    }
    acc += __shfl_xor(acc, 8);
    acc += __shfl_xor(acc, 16);
    acc += __shfl_xor(acc, 32);
    if(ks == 0)
        v_T[n*8 + b] = acc;
}

// ---- parallel partial sum of (u*v)^2 per sample -> ssq[b] ----
__global__ __launch_bounds__(256) void k_normp(const float* __restrict__ u,
                        const float* __restrict__ v_T, float* __restrict__ ssq){
    int t = threadIdx.x;
    float s = 0.f;
    #pragma unroll
    for(int c = 0; c < 4; c++){
        int idx = c*32768 + blockIdx.x*256 + t;
        int n = idx >> 3, b = idx & 7;
        float tv = u[b*Ndim + n] * v_T[idx];
        s = fmaf(tv, tv, s);
    }
    s += __shfl_xor(s, 8);
    s += __shfl_xor(s, 16);
    s += __shfl_xor(s, 32);
    if(((t & 63) >> 3) == 0) atomicAdd(&ssq[t & 7], s);
}

// ---- fully fused conv1+conv2+conv3 (conv2/3 MFMA bf16) ----
__global__ __launch_bounds__(256) void k_conv123(
        const float* __restrict__ z_cur, const float* __restrict__ u,
        const float* __restrict__ v_T, const float* __restrict__ ssq,
        const float* __restrict__ etas, const float* __restrict__ W1,
        const short* __restrict__ w2p, const short* __restrict__ w3p,
        int j, float* __restrict__ dst, float* __restrict__ zu_T){
    __shared__ short w2t[9*32*40];       // [kk][oc][ic] bf16 — 23 KB
    __shared__ short x1t[144*40];        // 12x12 px × 32 ic bf16 — 11.5 KB
    __shared__ short x2t[100*40];        // 10x10 px × 32 ic bf16 — 8 KB
    __shared__ float w1s[288];
    __shared__ short w3b[288];
    __shared__ float r14[196];
    int t = threadIdx.x;
    int blk = blockIdx.x;
    int bb = blk >> 8, tile = blk & 255;
    int oy0 = (tile >> 4)*8, ox0 = (tile & 15)*8;

    // stage pre-converted weights (uint4 = 8 bf16 per op)
    for(int idx = t; idx < 1440; idx += 256)
        ((uint4*)w2t)[idx] = ((const uint4*)(w2p + (size_t)j*11520))[idx];
    for(int idx = t; idx < 288; idx += 256){
        w1s[idx] = W1[j*288 + idx];
        w3b[idx] = w3p[j*288 + idx];
    }
    if(t < 196){
        int yy = t/14, xx = t%14;
        int gy = oy0 + yy - 3, gx = ox0 + xx - 3;
        float val = 0.f;
        if((unsigned)gy < 128u && (unsigned)gx < 128u){
            int n = gy*IMG + gx;
            int idx = bb*Ndim + n;
            float scale = etas[j] / fmaxf(1.0f, sqrtf(ssq[bb]));
            val = z_cur[idx] - scale * u[idx] * v_T[n*8 + bb];
        }
        r14[t] = val;
    }
    __syncthreads();

    // conv1 -> x1t (bf16), 2 adjacent oc per thread packed as one b32 write
    for(int idx = t; idx < 2304; idx += 256){
        int ocp = idx & 15, p = idx >> 4;
        int py = p/12, px = p%12;
        int gy = oy0 + py - 2, gx = ox0 + px - 2;
        float a0 = 0.f, a1 = 0.f;
        if((unsigned)gy < 128u && (unsigned)gx < 128u){
            #pragma unroll
            for(int ky = 0; ky < 3; ky++)
                #pragma unroll
                for(int kx = 0; kx < 3; kx++){
                    float rv = r14[(py+ky)*14 + (px+kx)];
                    a0 = fmaf(rv, w1s[(ky*3+kx)*32 + 2*ocp],     a0);
                    a1 = fmaf(rv, w1s[(ky*3+kx)*32 + 2*ocp + 1], a1);
                }
            a0 = fmaxf(a0, 0.f); a1 = fmaxf(a1, 0.f);
        }
        unsigned pack = (unsigned short)f2b(a0) | ((unsigned)(unsigned short)f2b(a1) << 16);
        ((unsigned*)x1t)[p*20 + ocp] = pack;
    }
    __syncthreads();

    int wv = t >> 6, lane = t & 63, mm = lane & 15, q = lane >> 4;

    // conv2 MFMA -> x2t (100 pixels in two 64-slot rounds); off-image pixels zeroed
    #pragma unroll
    for(int rnd = 0; rnd < 2; rnd++){
        int p = rnd*64 + wv*16 + mm;
        int pp = min(p, 99);
        int py2 = pp/10, px2 = pp%10;
        f4_t acc0 = {0.f,0.f,0.f,0.f}, acc1 = {0.f,0.f,0.f,0.f};
        #pragma unroll
        for(int kk = 0; kk < 9; kk++){
            int ky = kk/3, kx = kk%3;
            bf8_t a  = *(const bf8_t*)&x1t[((py2+ky)*12 + (px2+kx))*40 + q*8];
            bf8_t b0 = *(const bf8_t*)&w2t[(kk*32 + mm)*40 + q*8];
            bf8_t b1 = *(const bf8_t*)&w2t[(kk*32 + 16 + mm)*40 + q*8];
            acc0 = __builtin_amdgcn_mfma_f32_16x16x32_bf16(a, b0, acc0, 0, 0, 0);
            acc1 = __builtin_amdgcn_mfma_f32_16x16x32_bf16(a, b1, acc1, 0, 0, 0);
        }
        #pragma unroll
        for(int reg = 0; reg < 4; reg++){
            int pw = rnd*64 + wv*16 + q*4 + reg;
            if(pw < 100){
                int py = pw/10, px = pw%10;
                int gy = oy0 + py - 1, gx = ox0 + px - 1;
                bool in = ((unsigned)gy < 128u) && ((unsigned)gx < 128u);
                x2t[pw*40 + mm]      = in ? f2b(fmaxf(acc0[reg], 0.f)) : (short)0;
                x2t[pw*40 + mm + 16] = in ? f2b(fmaxf(acc1[reg], 0.f)) : (short)0;
            }
        }
    }
    __syncthreads();

    // conv3 MFMA: 64 output pixels = 4 waves × 16 rows; only col 0 consumed
    int p3 = wv*16 + mm;
    int py3 = p3 >> 3, px3 = p3 & 7;
    f4_t acc = {0.f,0.f,0.f,0.f};
    #pragma unroll
    for(int kk = 0; kk < 9; kk++){
        int ky = kk/3, kx = kk%3;
        bf8_t a = *(const bf8_t*)&x2t[((py3+ky)*10 + (px3+kx))*40 + q*8];
        bf8_t bf;
        #pragma unroll
        for(int jj = 0; jj < 8; jj++)
            bf[jj] = (mm == 0) ? w3b[kk*32 + q*8 + jj] : (short)0;
        acc = __builtin_amdgcn_mfma_f32_16x16x32_bf16(a, bf, acc, 0, 0, 0);
    }
    if(mm == 0){
        #pragma unroll
        for(int reg = 0; reg < 4; reg++){
            int po = wv*16 + q*4 + reg;
            int py = po >> 3, px = po & 7;
            int gy = oy0 + py, gx = ox0 + px;
            int n = gy*IMG + gx;
            int idx = bb*Ndim + n;
            float r = r14[(py+3)*14 + (px+3)];
            float znew = fmaxf(r + acc[reg], 0.f);
            dst[idx] = znew;
            zu_T[n*8 + bb] = znew * u[idx];
        }
    }
}

extern "C" void kernel_launch(void* const* d_in, const int* in_sizes, int n_in,
                              void* d_out, int out_size, void* d_ws, size_t ws_size,
                              hipStream_t stream){
    const float* A_vals = (const float*)d_in[0];
    const int* A_rows = (const int*)d_in[1];
    const int* A_cols = (const int*)d_in[2];
    const float* z_in = (const float*)d_in[3];
    const float* u    = (const float*)d_in[4];
    const float* y    = (const float*)d_in[5];
    const float* W1   = (const float*)d_in[6];
    const float* W2   = (const float*)d_in[7];
    const float* W3   = (const float*)d_in[8];
    const float* etas = (const float*)d_in[9];

    float* ws = (float*)d_ws;
    float* z_cur   = ws;  ws += Bsz*Ndim;
    float* zu_T    = ws;  ws += Ndim*8;
    float* v_T     = ws;  ws += Ndim*8;
    float* resid_T = ws;  ws += Mdim*8;
    float* ssq     = ws;  ws += 8;
    int*   row_cnt = (int*)ws; ws += Mdim;
    int*   col_cnt = (int*)ws; ws += Ndim;
    short* w2p     = (short*)ws; ws += 3*11520/2;        // 34560 shorts (16B-aligned)
    short* w3p     = (short*)ws; ws += 3*288/2 + 4;
    float2* rp = (float2*)ws; ws += (size_t)Mdim*RCAP*2;
    float2* cp = (float2*)ws;

    k_zeroc<<<(Mdim+Ndim)/256, 256, 0, stream>>>(row_cnt);
    k_prep<<<108, 256, 0, stream>>>(W2, W3, w2p, w3p);
    k_build_r<<<1024, 256, 0, stream>>>(A_vals, A_rows, A_cols, row_cnt, rp);
    k_build_c<<<1024, 256, 0, stream>>>(A_vals, A_rows, A_cols, col_cnt, cp);
    k_init<<<Bsz*Ndim/256, 256, 0, stream>>>(z_in, u, z_cur, zu_T);

    for(int j = 0; j < Jit; j++){
        k_spmm1g<<<Mdim/4, 256, 0, stream>>>(rp, row_cnt, y, zu_T, resid_T, ssq);
        k_spmm2g<<<Ndim/4, 256, 0, stream>>>(cp, col_cnt, resid_T, v_T);
        k_normp<<<128, 256, 0, stream>>>(u, v_T, ssq);
        float* dst = (j == Jit-1) ? (float*)d_out : z_cur;
        k_conv123<<<Bsz*256, 256, 0, stream>>>(z_cur, u, v_T, ssq, etas,
                                               W1, w2p, w3p, j, dst, zu_T);
    }
}